// Round 3
// baseline (1799.622 us; speedup 1.0000x reference)
//
#include <hip/hip_runtime.h>
#include <hip/hip_bf16.h>

#define T_TOK 8192
#define D_DIM 1024
#define H_DIM 4096
#define E_NUM 8

typedef short bf16x8 __attribute__((ext_vector_type(8)));
typedef float f32x4 __attribute__((ext_vector_type(4)));

__device__ __forceinline__ unsigned short f2bf(float f) {
    union { float f; unsigned int u; } v; v.f = f;
    unsigned int u = v.u;
    u = u + 0x7FFFu + ((u >> 16) & 1u);   // round-to-nearest-even
    return (unsigned short)(u >> 16);
}

__device__ __forceinline__ void gload_lds16(const void* g, void* l) {
    __builtin_amdgcn_global_load_lds(
        (const __attribute__((address_space(1))) unsigned int*)g,
        (__attribute__((address_space(3))) unsigned int*)l,
        16, 0, 0);
}

// ---------------- gating: one wave per token, fp64 accumulate ----------------
__global__ void gate_kernel(const float* __restrict__ x, const float* __restrict__ Wg,
                            const float* __restrict__ bg, float* __restrict__ wout) {
    int wv = (int)((blockIdx.x * blockDim.x + threadIdx.x) >> 6);  // token id
    int lane = threadIdx.x & 63;
    if (wv >= T_TOK) return;
    const float* xr = x + (size_t)wv * D_DIM;
    double acc[E_NUM] = {0, 0, 0, 0, 0, 0, 0, 0};
    for (int i = 0; i < D_DIM / 64; ++i) {
        int d = i * 64 + lane;
        double xv = (double)xr[d];
        const float* wr = Wg + (size_t)d * E_NUM;
        #pragma unroll
        for (int e = 0; e < E_NUM; ++e) acc[e] += xv * (double)wr[e];
    }
    #pragma unroll
    for (int e = 0; e < E_NUM; ++e) {
        double v = acc[e];
        for (int s = 32; s; s >>= 1) v += __shfl_down(v, s, 64);
        acc[e] = v;
    }
    if (lane == 0) {
        #pragma unroll
        for (int e = 0; e < E_NUM; ++e) {
            double z = acc[e] + (double)bg[e];
            float p = (float)(1.0 / (1.0 + exp(-z)));
            wout[(size_t)wv * E_NUM + e] = (p > 0.5f) ? p : 0.0f;
        }
    }
}

// ---------------- fp32 -> bf16 elementwise convert (X) ----------------
__global__ void cvt_kernel(const float* __restrict__ in, unsigned short* __restrict__ out, size_t n) {
    size_t i = ((size_t)blockIdx.x * blockDim.x + threadIdx.x) * 8;
    if (i >= n) return;
    float4 v0 = *(const float4*)(in + i);
    float4 v1 = *(const float4*)(in + i + 4);
    ushort4 o0, o1;
    o0.x = f2bf(v0.x); o0.y = f2bf(v0.y); o0.z = f2bf(v0.z); o0.w = f2bf(v0.w);
    o1.x = f2bf(v1.x); o1.y = f2bf(v1.y); o1.z = f2bf(v1.z); o1.w = f2bf(v1.w);
    *(ushort4*)(out + i) = o0;
    *(ushort4*)(out + i + 4) = o1;
}

// ------- per-expert transpose+convert: in[e][R][C] fp32 -> out[e][C][R] bf16 -------
__global__ void transpose_cvt(const float* __restrict__ in, unsigned short* __restrict__ out,
                              int R, int C) {
    __shared__ unsigned short tile[64][65];
    int e = blockIdx.z;
    const float* src = in + (size_t)e * R * C;
    unsigned short* dst = out + (size_t)e * R * C;
    int c0 = blockIdx.x * 64, r0 = blockIdx.y * 64;
    int t = threadIdx.x;
    int cc = (t & 15) * 4;
    int rr = t >> 4;
    #pragma unroll
    for (int p = 0; p < 4; ++p) {
        int r = rr + p * 16;
        float4 v = *(const float4*)(src + (size_t)(r0 + r) * C + c0 + cc);
        tile[cc + 0][r] = f2bf(v.x);
        tile[cc + 1][r] = f2bf(v.y);
        tile[cc + 2][r] = f2bf(v.z);
        tile[cc + 3][r] = f2bf(v.w);
    }
    __syncthreads();
    int rr4 = (t & 15) * 4;
    int cw = t >> 4;
    #pragma unroll
    for (int p = 0; p < 4; ++p) {
        int c = cw + p * 16;
        ushort4 o;
        o.x = tile[c][rr4 + 0];
        o.y = tile[c][rr4 + 1];
        o.z = tile[c][rr4 + 2];
        o.w = tile[c][rr4 + 3];
        *(ushort4*)(dst + (size_t)(c0 + c) * R + r0 + rr4) = o;
    }
}

// ---------------- sentinel: workspace too small marker ----------------
__global__ void sentinel_kernel(float* out, size_t n) {
    size_t i = (size_t)blockIdx.x * blockDim.x + threadIdx.x;
    size_t st = (size_t)gridDim.x * blockDim.x;
    for (; i < n; i += st) out[i] = 12345.0f;
}

// ---------------- GEMM, m97 structure: C[M,N] = A[M,K] * B[N,K]^T ----------------
// MODE 0: Hc[r][cn] = bf16(relu(acc + b1[cn]))                    (out = ushort*, stride H_DIM)
// MODE 1: out[t0+r][cn]  = w[t]*(acc + b2[cn])                    (out = float*, stride D_DIM)
// MODE 2: out[t0+r][cn] += w[t]*(acc + b2[cn])
template<int MODE>
__global__ __launch_bounds__(256) void gemm_bt(
    const unsigned short* __restrict__ A,
    const unsigned short* __restrict__ B,
    void* __restrict__ outp,
    const float* __restrict__ bias,
    const float* __restrict__ wts,
    int K, int t0, int e)
{
    __shared__ __align__(16) unsigned short lA[128 * 32];
    __shared__ __align__(16) unsigned short lB[128 * 32];
    const int tid = threadIdx.x;
    const int bm = blockIdx.y, bn = blockIdx.x;
    const int lane = tid & 63, wid = tid >> 6;
    const int wr = wid >> 1, wc = wid & 1;
    const int fr = lane & 15, fq = lane >> 4;

    const int srow = tid >> 2;          // 0..63 (staging row within half-tile)
    const int sk = (tid & 3) * 8;       // ushort offset within 32-wide K row

    const unsigned short* A0 = A + (size_t)(bm * 128 + srow) * K + sk;
    const unsigned short* A1 = A0 + (size_t)64 * K;
    const unsigned short* B0 = B + (size_t)(bn * 128 + srow) * K + sk;
    const unsigned short* B1 = B0 + (size_t)64 * K;

    unsigned short* lA0 = lA + wid * 512;          // wave-uniform LDS bases
    unsigned short* lA1 = lA + 2048 + wid * 512;
    unsigned short* lB0 = lB + wid * 512;
    unsigned short* lB1 = lB + 2048 + wid * 512;

    f32x4 acc[4][4];
    #pragma unroll
    for (int m = 0; m < 4; ++m)
        #pragma unroll
        for (int n = 0; n < 4; ++n)
            acc[m][n] = (f32x4){0.f, 0.f, 0.f, 0.f};

    for (int k0 = 0; k0 < K; k0 += 32) {
        __syncthreads();
        gload_lds16(A0 + k0, lA0);
        gload_lds16(A1 + k0, lA1);
        gload_lds16(B0 + k0, lB0);
        gload_lds16(B1 + k0, lB1);
        __syncthreads();
        bf16x8 af[4], bfr[4];
        #pragma unroll
        for (int m = 0; m < 4; ++m)
            af[m] = *(const bf16x8*)(lA + ((wr * 64 + m * 16 + fr) * 32 + fq * 8));
        #pragma unroll
        for (int n = 0; n < 4; ++n)
            bfr[n] = *(const bf16x8*)(lB + ((wc * 64 + n * 16 + fr) * 32 + fq * 8));
        #pragma unroll
        for (int m = 0; m < 4; ++m)
            #pragma unroll
            for (int n = 0; n < 4; ++n)
                acc[m][n] = __builtin_amdgcn_mfma_f32_16x16x32_bf16(af[m], bfr[n], acc[m][n], 0, 0, 0);
    }

    if (MODE == 0) {
        unsigned short* Hc = (unsigned short*)outp;
        #pragma unroll
        for (int m = 0; m < 4; ++m) {
            const int rbase = bm * 128 + wr * 64 + m * 16 + fq * 4;
            #pragma unroll
            for (int n = 0; n < 4; ++n) {
                const int cn = bn * 128 + wc * 64 + n * 16 + fr;
                const float bb = bias[cn];
                #pragma unroll
                for (int j = 0; j < 4; ++j) {
                    float v = fmaxf(acc[m][n][j] + bb, 0.0f);
                    Hc[(size_t)(rbase + j) * H_DIM + cn] = f2bf(v);
                }
            }
        }
    } else {
        float* outf = (float*)outp;
        #pragma unroll
        for (int m = 0; m < 4; ++m) {
            const int rbase = bm * 128 + wr * 64 + m * 16 + fq * 4;
            #pragma unroll
            for (int n = 0; n < 4; ++n) {
                const int cn = bn * 128 + wc * 64 + n * 16 + fr;
                const float bb = bias[cn];
                #pragma unroll
                for (int j = 0; j < 4; ++j) {
                    const int row = t0 + rbase + j;
                    const float w = wts[(size_t)row * E_NUM + e];
                    const float v = (acc[m][n][j] + bb) * w;
                    float* p = outf + (size_t)row * D_DIM + cn;
                    if (MODE == 1) *p = v;
                    else *p += v;
                }
            }
        }
    }
}

extern "C" void kernel_launch(void* const* d_in, const int* in_sizes, int n_in,
                              void* d_out, int out_size, void* d_ws, size_t ws_size,
                              hipStream_t stream) {
    const float* x  = (const float*)d_in[0];
    const float* Wg = (const float*)d_in[1];
    const float* bg = (const float*)d_in[2];
    const float* W1 = (const float*)d_in[3];
    const float* b1 = (const float*)d_in[4];
    const float* W2 = (const float*)d_in[5];
    const float* b2 = (const float*)d_in[6];
    float* out = (float*)d_out;
    char* ws = (char*)d_ws;

    const size_t off_w  = 0;                                        // weights: T*E*4 = 256 KiB
    const size_t off_x  = 262144;                                   // Xbf16: 16 MiB
    const size_t off_w1 = off_x + (size_t)T_TOK * D_DIM * 2;        // W1T bf16 [E][H][D]: 64 MiB
    const size_t off_w2 = off_w1 + (size_t)E_NUM * D_DIM * H_DIM * 2; // W2T bf16 [E][D][H]: 64 MiB
    const size_t off_h  = off_w2 + (size_t)E_NUM * D_DIM * H_DIM * 2; // Hc bf16 [TC][H]
    const size_t min_h  = (size_t)128 * H_DIM * 2;

    if (ws_size < off_h + min_h) {
        sentinel_kernel<<<2048, 256, 0, stream>>>(out, (size_t)T_TOK * D_DIM);
        return;
    }
    size_t avail = ws_size - off_h;
    size_t tc = avail / ((size_t)H_DIM * 2);
    tc = (tc / 128) * 128;
    if (tc > T_TOK) tc = T_TOK;
    const int TC = (int)tc;

    float* wgt = (float*)(ws + off_w);
    unsigned short* Xb  = (unsigned short*)(ws + off_x);
    unsigned short* W1T = (unsigned short*)(ws + off_w1);
    unsigned short* W2T = (unsigned short*)(ws + off_w2);
    unsigned short* Hc  = (unsigned short*)(ws + off_h);

    gate_kernel<<<T_TOK / 4, 256, 0, stream>>>(x, Wg, bg, wgt);
    cvt_kernel<<<(T_TOK * (size_t)D_DIM / 8 + 255) / 256, 256, 0, stream>>>(x, Xb, (size_t)T_TOK * D_DIM);
    transpose_cvt<<<dim3(H_DIM / 64, D_DIM / 64, E_NUM), 256, 0, stream>>>(W1, W1T, D_DIM, H_DIM);
    transpose_cvt<<<dim3(D_DIM / 64, H_DIM / 64, E_NUM), 256, 0, stream>>>(W2, W2T, H_DIM, D_DIM);

    for (int t0 = 0; t0 < T_TOK; t0 += TC) {
        int cs = (T_TOK - t0 < TC) ? (T_TOK - t0) : TC;
        dim3 g1(H_DIM / 128, cs / 128);
        dim3 g2(D_DIM / 128, cs / 128);
        for (int e = 0; e < E_NUM; ++e) {
            gemm_bt<0><<<g1, 256, 0, stream>>>(
                Xb + (size_t)t0 * D_DIM, W1T + (size_t)e * D_DIM * H_DIM,
                Hc, b1 + (size_t)e * H_DIM, (const float*)nullptr, D_DIM, 0, e);
            if (e == 0)
                gemm_bt<1><<<g2, 256, 0, stream>>>(
                    Hc, W2T + (size_t)e * D_DIM * H_DIM,
                    out, b2 + (size_t)e * D_DIM, wgt, H_DIM, t0, e);
            else
                gemm_bt<2><<<g2, 256, 0, stream>>>(
                    Hc, W2T + (size_t)e * D_DIM * H_DIM,
                    out, b2 + (size_t)e * D_DIM, wgt, H_DIM, t0, e);
        }
    }
}